// Round 1
// baseline (429.851 us; speedup 1.0000x reference)
//
#include <hip/hip_runtime.h>
#include <math.h>

constexpr int B_   = 4096;
constexpr int C_   = 100;
constexpr int D_   = 128;
constexpr int TWOB = 2 * B_;        // 8192
constexpr int NJ   = TWOB + C_;     // 8292
constexpr float INV_T = 10.0f;      // 1 / 0.1

// ws layout (floats): [0,128): int cnt[100] (padded); [128, 128+8192): E; [+8192): S
// total 16512 floats ~ 66 KB

__device__ __forceinline__ const float* feat_row(const float* __restrict__ centers,
                                                 const float* __restrict__ features,
                                                 int idx) {
  if (idx < B_)   return features + (size_t)idx * (2 * D_);           // view 0
  if (idx < TWOB) return features + (size_t)(idx - B_) * (2 * D_) + D_; // view 1
  return centers + (size_t)(idx - TWOB) * D_;                          // class centers
}

__global__ void zero_kernel(float* ws) {
  int i = blockIdx.x * 256 + threadIdx.x;
  if (i < 128 + 2 * TWOB) ws[i] = 0.f;
}

__global__ void count_kernel(const int* __restrict__ targets, int* __restrict__ cnt) {
  int i = blockIdx.x * 256 + threadIdx.x;
  if (i < B_) atomicAdd(&cnt[targets[i]], 1);
}

__global__ __launch_bounds__(256)
void bal_main(const float* __restrict__ centers, const float* __restrict__ features,
              const int* __restrict__ targets, const int* __restrict__ cnt,
              float* __restrict__ Eacc, float* __restrict__ Sacc) {
  // K-major LDS tiles: [k][row] so fragment reads are contiguous float4s
  __shared__ float As[32][128];
  __shared__ float Bs[32][128];
  __shared__ int   tgtI[128];
  __shared__ int   tgtJ[128];
  __shared__ float bccJ[128];

  const int t  = threadIdx.x;
  const int i0 = blockIdx.y * 128;
  const int j0 = blockIdx.x * 128;

  if (t < 128) {
    int i = i0 + t;
    tgtI[t] = targets[i < B_ ? i : i - B_];
    int j = j0 + t;
    int jt = -1;
    if (j < B_)        jt = targets[j];
    else if (j < TWOB) jt = targets[j - B_];
    else if (j < NJ)   jt = j - TWOB;
    tgtJ[t] = jt;
    bccJ[t] = (jt >= 0) ? (float)(2 * cnt[jt] + 1) : 1.0f;
  }

  const int tr = t >> 4;   // 0..15
  const int tc = t & 15;   // 0..15

  float acc[8][8];
  #pragma unroll
  for (int a = 0; a < 8; ++a)
    #pragma unroll
    for (int b = 0; b < 8; ++b) acc[a][b] = 0.f;

  for (int kb = 0; kb < D_; kb += 32) {
    __syncthreads();
    // stage A (128 rows x 32 k) and B, transposed into K-major LDS
    #pragma unroll
    for (int l = 0; l < 4; ++l) {
      int f4  = t + l * 256;        // 0..1023
      int row = f4 >> 3;            // 0..127
      int k4  = (f4 & 7) << 2;      // 0,4,...,28
      float4 va = *(const float4*)(feat_row(centers, features, i0 + row) + kb + k4);
      As[k4 + 0][row] = va.x; As[k4 + 1][row] = va.y;
      As[k4 + 2][row] = va.z; As[k4 + 3][row] = va.w;
      int j = j0 + row;
      float4 vb = make_float4(0.f, 0.f, 0.f, 0.f);
      if (j < NJ) vb = *(const float4*)(feat_row(centers, features, j) + kb + k4);
      Bs[k4 + 0][row] = vb.x; Bs[k4 + 1][row] = vb.y;
      Bs[k4 + 2][row] = vb.z; Bs[k4 + 3][row] = vb.w;
    }
    __syncthreads();
    #pragma unroll
    for (int k = 0; k < 32; ++k) {
      float a[8], b[8];
      *(float4*)&a[0] = *(const float4*)&As[k][tr * 4];
      *(float4*)&a[4] = *(const float4*)&As[k][tr * 4 + 64];
      *(float4*)&b[0] = *(const float4*)&Bs[k][tc * 4];
      *(float4*)&b[4] = *(const float4*)&Bs[k][tc * 4 + 64];
      #pragma unroll
      for (int ri = 0; ri < 8; ++ri)
        #pragma unroll
        for (int ci = 0; ci < 8; ++ci)
          acc[ri][ci] += a[ri] * b[ci];
    }
  }

  // fused epilogue: s = acc*10; E += exp(s)/(bcc - m); S += m*s
  float ep[8], sp[8];
  #pragma unroll
  for (int ri = 0; ri < 8; ++ri) { ep[ri] = 0.f; sp[ri] = 0.f; }

  #pragma unroll
  for (int ci = 0; ci < 8; ++ci) {
    int jj = tc * 4 + (ci & 3) + ((ci >> 2) << 6);
    int j  = j0 + jj;
    int jt = tgtJ[jj];
    float bw = bccJ[jj];
    bool jv = (j < NJ);
    #pragma unroll
    for (int ri = 0; ri < 8; ++ri) {
      int ii = tr * 4 + (ri & 3) + ((ri >> 2) << 6);
      int i  = i0 + ii;
      float s = acc[ri][ci] * INV_T;
      bool nz = jv && (j != i);
      bool m  = nz && (tgtI[ii] == jt);
      if (nz) ep[ri] += __expf(s) / (bw - (m ? 1.f : 0.f));
      if (m)  sp[ri] += s;
    }
  }

  // reduce across the 16 tc-lanes (contiguous within a wave)
  #pragma unroll
  for (int mk = 1; mk <= 8; mk <<= 1) {
    #pragma unroll
    for (int ri = 0; ri < 8; ++ri) {
      ep[ri] += __shfl_xor(ep[ri], mk, 64);
      sp[ri] += __shfl_xor(sp[ri], mk, 64);
    }
  }
  if (tc == 0) {
    #pragma unroll
    for (int ri = 0; ri < 8; ++ri) {
      int ii = tr * 4 + (ri & 3) + ((ri >> 2) << 6);
      atomicAdd(&Eacc[i0 + ii], ep[ri]);
      atomicAdd(&Sacc[i0 + ii], sp[ri]);
    }
  }
}

__global__ __launch_bounds__(256)
void bal_final(const int* __restrict__ targets, const int* __restrict__ cnt,
               const float* __restrict__ Eacc, const float* __restrict__ Sacc,
               float* __restrict__ out) {
  int t = threadIdx.x;
  float local = 0.f;
  for (int i = t; i < TWOB; i += 256) {
    int ti = targets[i < B_ ? i : i - B_];
    float nmask = (float)(2 * cnt[ti]);
    local += Sacc[i] / nmask - logf(Eacc[i]);
  }
  #pragma unroll
  for (int mk = 1; mk < 64; mk <<= 1) local += __shfl_xor(local, mk, 64);
  __shared__ float red[4];
  if ((t & 63) == 0) red[t >> 6] = local;
  __syncthreads();
  if (t == 0) out[0] = -(red[0] + red[1] + red[2] + red[3]) / (float)TWOB;
}

extern "C" void kernel_launch(void* const* d_in, const int* in_sizes, int n_in,
                              void* d_out, int out_size, void* d_ws, size_t ws_size,
                              hipStream_t stream) {
  const float* centers  = (const float*)d_in[0];
  const float* features = (const float*)d_in[1];
  const int*   targets  = (const int*)d_in[2];
  float* wsf  = (float*)d_ws;
  int*   cnt  = (int*)d_ws;
  float* Eacc = wsf + 128;
  float* Sacc = wsf + 128 + TWOB;
  float* out  = (float*)d_out;

  zero_kernel<<<(128 + 2 * TWOB + 255) / 256, 256, 0, stream>>>(wsf);
  count_kernel<<<(B_ + 255) / 256, 256, 0, stream>>>(targets, cnt);
  dim3 grid((NJ + 127) / 128, TWOB / 128);   // (65, 64)
  bal_main<<<grid, 256, 0, stream>>>(centers, features, targets, cnt, Eacc, Sacc);
  bal_final<<<1, 256, 0, stream>>>(targets, cnt, Eacc, Sacc, out);
}

// Round 2
// 189.514 us; speedup vs baseline: 2.2682x; 2.2682x over previous
//
#include <hip/hip_runtime.h>
#include <math.h>

constexpr int B_   = 4096;
constexpr int C_   = 100;
constexpr int D_   = 128;
constexpr int TWOB = 2 * B_;        // 8192
constexpr int NJ   = TWOB + C_;     // 8292
constexpr int NJP  = 8320;          // padded to 65*128

typedef __attribute__((ext_vector_type(8))) short short8;
typedef __attribute__((ext_vector_type(4))) float f32x4;

// ---------------- ws layout (bytes) ----------------
// 0      : int   cnt[128]        (512 B)
// 512    : float Eacc[8192]      (32768)
// 33280  : float Sacc[8192]      (32768)
// 66048  : int   tgtAll[8320]    (33280)
// 99328  : float rcp0[8320]      (33280)
// 132608 : float rcp1[8320]      (33280)
// 165888 : ushort featbf[8320*128] (2129920)  -> total ~2.3 MB

__device__ __forceinline__ const float* feat_row(const float* __restrict__ centers,
                                                 const float* __restrict__ features,
                                                 int idx) {
  if (idx < B_)   return features + (size_t)idx * (2 * D_);
  if (idx < TWOB) return features + (size_t)(idx - B_) * (2 * D_) + D_;
  return centers + (size_t)(idx - TWOB) * D_;
}

__device__ __forceinline__ unsigned short f2bf(float x) {
  unsigned int u = __float_as_uint(x);
  unsigned int r = (u + 0x7FFFu + ((u >> 16) & 1u)) >> 16;   // RNE
  return (unsigned short)r;
}

__global__ void zero_kernel(float* ws) {
  int i = blockIdx.x * 256 + threadIdx.x;
  if (i < 128 + 2 * TWOB) ws[i] = 0.f;
}

__global__ void count_kernel(const int* __restrict__ targets, int* __restrict__ cnt) {
  int i = blockIdx.x * 256 + threadIdx.x;
  if (i < B_) atomicAdd(&cnt[targets[i]], 1);
}

// convert feats -> bf16 (padded, zero-filled) + per-j target / reciprocal tables
__global__ __launch_bounds__(256)
void prep_kernel(const float* __restrict__ centers, const float* __restrict__ features,
                 const int* __restrict__ targets, const int* __restrict__ cnt,
                 unsigned short* __restrict__ fb, int* __restrict__ tgtAll,
                 float* __restrict__ rcp0, float* __restrict__ rcp1) {
  int g = blockIdx.x * 256 + threadIdx.x;      // 8320*32 items
  if (g >= NJP * 32) return;
  int row = g >> 5;
  int q   = g & 31;                            // float4 index within row
  float4 v = make_float4(0.f, 0.f, 0.f, 0.f);
  if (row < NJ) v = *(const float4*)(feat_row(centers, features, row) + q * 4);
  ushort4 o;
  o.x = f2bf(v.x); o.y = f2bf(v.y); o.z = f2bf(v.z); o.w = f2bf(v.w);
  *(ushort4*)&fb[(size_t)row * 128 + q * 4] = o;
  if (q == 0) {
    int jt;
    if (row < B_)        jt = targets[row];
    else if (row < TWOB) jt = targets[row - B_];
    else if (row < NJ)   jt = row - TWOB;
    else                 jt = -9;
    tgtAll[row] = jt;
    if (jt >= 0) {
      float b = (float)(2 * cnt[jt] + 1);
      rcp0[row] = 1.f / b;
      rcp1[row] = 1.f / (b - 1.f);    // inf only if cnt==0, then never selected
    } else {
      rcp0[row] = 0.f;                // padded columns contribute nothing
      rcp1[row] = 0.f;
    }
  }
}

__global__ __launch_bounds__(256, 2)
void bal_mfma(const unsigned short* __restrict__ fb, const int* __restrict__ tgtAll,
              const float* __restrict__ rcp0, const float* __restrict__ rcp1,
              float* __restrict__ Eacc, float* __restrict__ Sacc) {
  __shared__ unsigned short Ab[128 * 128];   // 32 KB, chunk-swizzled rows
  __shared__ unsigned short Bb[128 * 128];   // 32 KB

  const int t    = threadIdx.x;
  const int lane = t & 63;
  const int wid  = t >> 6;          // 0..3
  const int wr   = wid >> 1;        // wave row (0..1)
  const int wc   = wid & 1;         // wave col (0..1)
  const int lr   = lane & 15;
  const int lh   = lane >> 4;       // 0..3
  const int i0   = blockIdx.y * 128;
  const int j0   = blockIdx.x * 128;

  // ---- stage A and B tiles: global_load_lds w=16, pre-swizzled global source ----
  // LDS[row][chunk c'] holds global chunk c' ^ (row&7)   (chunk = 16B = 8 bf16)
  #pragma unroll
  for (int q = 0; q < 8; ++q) {
    int r0   = wid * 32 + q * 4;                 // 4 rows per instruction
    int row  = r0 + (lane >> 4);                 // here lane>>4 in 0..3
    int chk  = (lane & 15) ^ (row & 7);
    const unsigned short* ga = fb + (size_t)(i0 + row) * 128 + chk * 8;
    const unsigned short* gb = fb + (size_t)(j0 + row) * 128 + chk * 8;
    __builtin_amdgcn_global_load_lds(
        (const __attribute__((address_space(1))) unsigned int*)ga,
        (__attribute__((address_space(3))) unsigned int*)&Ab[r0 * 128], 16, 0, 0);
    __builtin_amdgcn_global_load_lds(
        (const __attribute__((address_space(1))) unsigned int*)gb,
        (__attribute__((address_space(3))) unsigned int*)&Bb[r0 * 128], 16, 0, 0);
  }
  __syncthreads();

  // ---- MFMA: wave computes 64x64, 4x4 frags of 16x16, K=128 in 4 steps ----
  f32x4 acc[4][4];
  #pragma unroll
  for (int m = 0; m < 4; ++m)
    #pragma unroll
    for (int n = 0; n < 4; ++n) acc[m][n] = (f32x4){0.f, 0.f, 0.f, 0.f};

  #pragma unroll
  for (int ks = 0; ks < 4; ++ks) {
    short8 af[4], bf[4];
    #pragma unroll
    for (int m = 0; m < 4; ++m) {
      int row = wr * 64 + m * 16 + lr;
      int chk = (ks * 4 + lh) ^ (row & 7);
      af[m] = *(const short8*)&Ab[row * 128 + chk * 8];
    }
    #pragma unroll
    for (int n = 0; n < 4; ++n) {
      int row = wc * 64 + n * 16 + lr;
      int chk = (ks * 4 + lh) ^ (row & 7);
      bf[n] = *(const short8*)&Bb[row * 128 + chk * 8];
    }
    #pragma unroll
    for (int m = 0; m < 4; ++m)
      #pragma unroll
      for (int n = 0; n < 4; ++n)
        acc[m][n] = __builtin_amdgcn_mfma_f32_16x16x32_bf16(af[m], bf[n], acc[m][n], 0, 0, 0);
  }

  // ---- fused epilogue ----
  // C/D layout: col = lane&15 (j), row = (lane>>4)*4 + reg (i)
  int   jt_n[4];
  float r0_n[4], r1_n[4];
  #pragma unroll
  for (int n = 0; n < 4; ++n) {
    int jc = j0 + wc * 64 + n * 16 + lr;
    jt_n[n] = tgtAll[jc];
    r0_n[n] = rcp0[jc];
    r1_n[n] = rcp1[jc];
  }
  int ti[4][4];
  #pragma unroll
  for (int m = 0; m < 4; ++m)
    #pragma unroll
    for (int g = 0; g < 4; ++g)
      ti[m][g] = tgtAll[i0 + wr * 64 + m * 16 + lh * 4 + g];

  float ep[4][4], ma[4][4];
  #pragma unroll
  for (int m = 0; m < 4; ++m)
    #pragma unroll
    for (int g = 0; g < 4; ++g) { ep[m][g] = 0.f; ma[m][g] = 0.f; }

  #pragma unroll
  for (int m = 0; m < 4; ++m) {
    #pragma unroll
    for (int n = 0; n < 4; ++n) {
      int j = j0 + wc * 64 + n * 16 + lr;
      #pragma unroll
      for (int g = 0; g < 4; ++g) {
        int i = i0 + wr * 64 + m * 16 + lh * 4 + g;
        float a = acc[m][n][g];
        float e = __builtin_amdgcn_exp2f(a * 14.4269504089f);  // exp(10a)
        bool eq   = (ti[m][g] == jt_n[n]);
        bool diag = (i == j);
        float r = eq ? (diag ? 0.f : r1_n[n]) : r0_n[n];
        ep[m][g] += e * r;
        ma[m][g] += (eq && !diag) ? a : 0.f;
      }
    }
  }

  // reduce over the 16 column-lanes (same rows within each 16-lane group)
  #pragma unroll
  for (int mk = 1; mk <= 8; mk <<= 1) {
    #pragma unroll
    for (int m = 0; m < 4; ++m)
      #pragma unroll
      for (int g = 0; g < 4; ++g) {
        ep[m][g] += __shfl_xor(ep[m][g], mk, 64);
        ma[m][g] += __shfl_xor(ma[m][g], mk, 64);
      }
  }
  if (lr == 0) {
    #pragma unroll
    for (int m = 0; m < 4; ++m)
      #pragma unroll
      for (int g = 0; g < 4; ++g) {
        int i = i0 + wr * 64 + m * 16 + lh * 4 + g;
        atomicAdd(&Eacc[i], ep[m][g]);
        atomicAdd(&Sacc[i], ma[m][g]);
      }
  }
}

__global__ __launch_bounds__(256)
void bal_final(const int* __restrict__ tgtAll, const float* __restrict__ rcp1,
               const float* __restrict__ Eacc, const float* __restrict__ Sacc,
               float* __restrict__ out) {
  int t = threadIdx.x;
  float local = 0.f;
  for (int i = t; i < TWOB; i += 256) {
    // mean_log_prob_pos = 10*Sacc/(2*cnt) - log(Eacc);  rcp1[i] = 1/(2*cnt[tgt_i])
    local += 10.f * Sacc[i] * rcp1[i] - logf(Eacc[i]);
  }
  #pragma unroll
  for (int mk = 1; mk < 64; mk <<= 1) local += __shfl_xor(local, mk, 64);
  __shared__ float red[4];
  if ((t & 63) == 0) red[t >> 6] = local;
  __syncthreads();
  if (t == 0) out[0] = -(red[0] + red[1] + red[2] + red[3]) / (float)TWOB;
}

extern "C" void kernel_launch(void* const* d_in, const int* in_sizes, int n_in,
                              void* d_out, int out_size, void* d_ws, size_t ws_size,
                              hipStream_t stream) {
  const float* centers  = (const float*)d_in[0];
  const float* features = (const float*)d_in[1];
  const int*   targets  = (const int*)d_in[2];

  char* ws = (char*)d_ws;
  int*            cnt    = (int*)ws;
  float*          Eacc   = (float*)(ws + 512);
  float*          Sacc   = (float*)(ws + 33280);
  int*            tgtAll = (int*)(ws + 66048);
  float*          rcp0   = (float*)(ws + 99328);
  float*          rcp1   = (float*)(ws + 132608);
  unsigned short* fb     = (unsigned short*)(ws + 165888);
  float* out = (float*)d_out;

  zero_kernel<<<(128 + 2 * TWOB + 255) / 256, 256, 0, stream>>>((float*)ws);
  count_kernel<<<(B_ + 255) / 256, 256, 0, stream>>>(targets, cnt);
  prep_kernel<<<(NJP * 32 + 255) / 256, 256, 0, stream>>>(centers, features, targets, cnt,
                                                          fb, tgtAll, rcp0, rcp1);
  dim3 grid(NJP / 128, TWOB / 128);   // (65, 64)
  bal_mfma<<<grid, 256, 0, stream>>>(fb, tgtAll, rcp0, rcp1, Eacc, Sacc);
  bal_final<<<1, 256, 0, stream>>>(tgtAll, rcp1, Eacc, Sacc, out);
}

// Round 3
// 169.673 us; speedup vs baseline: 2.5334x; 1.1169x over previous
//
#include <hip/hip_runtime.h>
#include <math.h>

constexpr int B_   = 4096;
constexpr int C_   = 100;
constexpr int D_   = 128;
constexpr int TWOB = 2 * B_;        // 8192
constexpr int NJ   = TWOB + C_;     // 8292
constexpr int NJP  = 8320;          // 65*128
constexpr float LOG2E10 = 14.4269504089f;   // 10 * log2(e)
constexpr float LN2     = 0.6931471806f;

typedef __attribute__((ext_vector_type(8))) short short8;
typedef __attribute__((ext_vector_type(4))) float f32x4;

// ---------------- ws layout (bytes) ----------------
// 0       : int   cnt[128]          (512)
// 512     : float Eacc[8192]        (32768)
// 33280   : float Sacc[8192]        (32768)
// 66048   : int   tgtAll[8320]      (33280)
// 99328   : float rcp0[8320]        (33280)
// 132608  : float rcp1[8320]        (33280)
// 165888  : ushort fbB[8320*128]    (2129920)   unscaled bf16
// 2295808 : ushort fbA[8192*128]    (2097152)   bf16 of feats * 14.4269504
// total ~4.4 MB

__device__ __forceinline__ const float* feat_row(const float* __restrict__ centers,
                                                 const float* __restrict__ features,
                                                 int idx) {
  if (idx < B_)   return features + (size_t)idx * (2 * D_);
  if (idx < TWOB) return features + (size_t)(idx - B_) * (2 * D_) + D_;
  return centers + (size_t)(idx - TWOB) * D_;
}

__device__ __forceinline__ unsigned short f2bf(float x) {
  unsigned int u = __float_as_uint(x);
  unsigned int r = (u + 0x7FFFu + ((u >> 16) & 1u)) >> 16;   // RNE
  return (unsigned short)r;
}

__global__ void count_kernel(const int* __restrict__ targets, int* __restrict__ cnt) {
  int i = blockIdx.x * 256 + threadIdx.x;
  if (i < B_) atomicAdd(&cnt[targets[i]], 1);
}

__global__ __launch_bounds__(256)
void prep_kernel(const float* __restrict__ centers, const float* __restrict__ features,
                 const int* __restrict__ targets, const int* __restrict__ cnt,
                 unsigned short* __restrict__ fbB, unsigned short* __restrict__ fbA,
                 int* __restrict__ tgtAll, float* __restrict__ rcp0,
                 float* __restrict__ rcp1) {
  int g = blockIdx.x * 256 + threadIdx.x;      // NJP*32 items
  if (g >= NJP * 32) return;
  int row = g >> 5;
  int q   = g & 31;                            // float4 index within row
  float4 v = make_float4(0.f, 0.f, 0.f, 0.f);
  if (row < NJ) v = *(const float4*)(feat_row(centers, features, row) + q * 4);
  ushort4 o;
  o.x = f2bf(v.x); o.y = f2bf(v.y); o.z = f2bf(v.z); o.w = f2bf(v.w);
  *(ushort4*)&fbB[(size_t)row * 128 + q * 4] = o;
  if (row < TWOB) {
    ushort4 a;
    a.x = f2bf(v.x * LOG2E10); a.y = f2bf(v.y * LOG2E10);
    a.z = f2bf(v.z * LOG2E10); a.w = f2bf(v.w * LOG2E10);
    *(ushort4*)&fbA[(size_t)row * 128 + q * 4] = a;
  }
  if (q == 0) {
    int jt;
    if (row < B_)        jt = targets[row];
    else if (row < TWOB) jt = targets[row - B_];
    else if (row < NJ)   jt = row - TWOB;
    else                 jt = -9;
    tgtAll[row] = jt;
    if (jt >= 0) {
      float b = (float)(2 * cnt[jt] + 1);
      rcp0[row] = 1.f / b;
      rcp1[row] = 1.f / (b - 1.f);   // inf only if cnt==0, then never selected
    } else {
      rcp0[row] = 0.f;               // padded columns contribute nothing
      rcp1[row] = 0.f;
    }
  }
}

__global__ __launch_bounds__(256, 2)
void bal_mfma(const unsigned short* __restrict__ fbA, const unsigned short* __restrict__ fbB,
              const int* __restrict__ tgtAll, const float* __restrict__ rcp0,
              const float* __restrict__ rcp1,
              float* __restrict__ Eacc, float* __restrict__ Sacc) {
  __shared__ unsigned short Bb[2][128 * 128];   // 2 x 32 KB, chunk-swizzled rows

  const int t    = threadIdx.x;
  const int lane = t & 63;
  const int wid  = t >> 6;          // 0..3
  const int wr   = wid >> 1;        // wave row (0..1)
  const int wc   = wid & 1;         // wave col (0..1)
  const int lr   = lane & 15;
  const int lh   = lane >> 4;       // 0..3
  const int i0   = blockIdx.x * 128;
  const int s    = blockIdx.y;
  const int jt0  = (s == 0) ? 0 : 9 + 8 * (s - 1);
  const int jt1  = (s == 0) ? 9 : jt0 + 8;

  // ---- load A fragments once into registers (scaled copy) ----
  short8 af[4][4];                  // [ks][m]
  #pragma unroll
  for (int ks = 0; ks < 4; ++ks)
    #pragma unroll
    for (int m = 0; m < 4; ++m) {
      int row = i0 + wr * 64 + m * 16 + lr;
      af[ks][m] = *(const short8*)&fbA[(size_t)row * 128 + (ks * 4 + lh) * 8];
    }

  // i-side targets for this thread's accumulator rows
  int ti[4][4];
  #pragma unroll
  for (int m = 0; m < 4; ++m)
    #pragma unroll
    for (int g = 0; g < 4; ++g)
      ti[m][g] = tgtAll[i0 + wr * 64 + m * 16 + lh * 4 + g];

  float ep[4][4], ma[4][4];
  #pragma unroll
  for (int m = 0; m < 4; ++m)
    #pragma unroll
    for (int g = 0; g < 4; ++g) { ep[m][g] = 0.f; ma[m][g] = 0.f; }

  // ---- B staging: global_load_lds w=16, pre-swizzled global source ----
  // LDS[row][chunk c'] holds global chunk c' ^ (row&7)   (chunk = 16B = 8 bf16)
  auto stageB = [&](int buf, int jt) {
    const unsigned short* base = fbB + (size_t)jt * 128 * 128;
    #pragma unroll
    for (int q = 0; q < 8; ++q) {
      int r0  = wid * 32 + q * 4;              // 4 rows per instruction
      int row = r0 + (lane >> 4);
      int chk = (lane & 15) ^ (row & 7);
      __builtin_amdgcn_global_load_lds(
          (const __attribute__((address_space(1))) unsigned int*)(base + (size_t)row * 128 + chk * 8),
          (__attribute__((address_space(3))) unsigned int*)&Bb[buf][r0 * 128], 16, 0, 0);
    }
  };

  stageB(0, jt0);
  __syncthreads();

  for (int jt = jt0; jt < jt1; ++jt) {
    const int cur = (jt - jt0) & 1;
    if (jt + 1 < jt1) stageB(cur ^ 1, jt + 1);
    const int j0 = jt * 128;

    // per-tile j-column tables (L2-hit loads, overlap with MFMA scheduling)
    int jt_n[4]; float r0_n[4], r1_n[4];
    #pragma unroll
    for (int n = 0; n < 4; ++n) {
      int jc = j0 + wc * 64 + n * 16 + lr;
      jt_n[n] = tgtAll[jc];
      r0_n[n] = rcp0[jc];
      r1_n[n] = rcp1[jc];
    }

    // ---- MFMA: wave computes 64x64, K=128 in 4 steps ----
    f32x4 acc[4][4];
    #pragma unroll
    for (int m = 0; m < 4; ++m)
      #pragma unroll
      for (int n = 0; n < 4; ++n) acc[m][n] = (f32x4){0.f, 0.f, 0.f, 0.f};

    #pragma unroll
    for (int ks = 0; ks < 4; ++ks) {
      short8 bf[4];
      #pragma unroll
      for (int n = 0; n < 4; ++n) {
        int row = wc * 64 + n * 16 + lr;
        int chk = (ks * 4 + lh) ^ (row & 7);
        bf[n] = *(const short8*)&Bb[cur][row * 128 + chk * 8];
      }
      #pragma unroll
      for (int m = 0; m < 4; ++m)
        #pragma unroll
        for (int n = 0; n < 4; ++n)
          acc[m][n] = __builtin_amdgcn_mfma_f32_16x16x32_bf16(af[ks][m], bf[n], acc[m][n], 0, 0, 0);
    }

    // ---- fused epilogue: acc is 14.4269504*dot ;  exp(10*dot) = exp2(acc) ----
    if (j0 == i0) {
      #pragma unroll
      for (int m = 0; m < 4; ++m)
        #pragma unroll
        for (int n = 0; n < 4; ++n) {
          int jl = wc * 64 + n * 16 + lr;
          #pragma unroll
          for (int g = 0; g < 4; ++g) {
            int il = wr * 64 + m * 16 + lh * 4 + g;
            float a = acc[m][n][g];
            float e = __builtin_amdgcn_exp2f(a);
            bool eq   = (ti[m][g] == jt_n[n]);
            bool diag = (il == jl);
            float r = eq ? (diag ? 0.f : r1_n[n]) : r0_n[n];
            ep[m][g] += e * r;
            ma[m][g] += (eq && !diag) ? a : 0.f;
          }
        }
    } else {
      #pragma unroll
      for (int m = 0; m < 4; ++m)
        #pragma unroll
        for (int n = 0; n < 4; ++n) {
          #pragma unroll
          for (int g = 0; g < 4; ++g) {
            float a = acc[m][n][g];
            float e = __builtin_amdgcn_exp2f(a);
            bool eq = (ti[m][g] == jt_n[n]);
            ep[m][g] += e * (eq ? r1_n[n] : r0_n[n]);
            ma[m][g] += eq ? a : 0.f;
          }
        }
    }
    __syncthreads();   // all waves done with Bb[cur]; next-tile loads drained
  }

  // ---- reduce over the 16 column-lanes, one atomic set per block ----
  #pragma unroll
  for (int mk = 1; mk <= 8; mk <<= 1) {
    #pragma unroll
    for (int m = 0; m < 4; ++m)
      #pragma unroll
      for (int g = 0; g < 4; ++g) {
        ep[m][g] += __shfl_xor(ep[m][g], mk, 64);
        ma[m][g] += __shfl_xor(ma[m][g], mk, 64);
      }
  }
  if (lr == 0) {
    #pragma unroll
    for (int m = 0; m < 4; ++m)
      #pragma unroll
      for (int g = 0; g < 4; ++g) {
        int i = i0 + wr * 64 + m * 16 + lh * 4 + g;
        atomicAdd(&Eacc[i], ep[m][g]);
        atomicAdd(&Sacc[i], ma[m][g]);
      }
  }
}

__global__ __launch_bounds__(256)
void bal_final(const int* __restrict__ tgtAll, const int* __restrict__ cnt,
               const float* __restrict__ Eacc, const float* __restrict__ Sacc,
               float* __restrict__ out) {
  int i = blockIdx.x * 256 + threadIdx.x;   // 32 blocks x 256 = 8192
  int ti = tgtAll[i];
  float rc = 1.f / (float)(2 * cnt[ti]);
  // Sacc holds sum of mask * (14.4269504*dot); logit = 10*dot = ln2 * that
  float local = LN2 * Sacc[i] * rc - logf(Eacc[i]);
  #pragma unroll
  for (int mk = 1; mk < 64; mk <<= 1) local += __shfl_xor(local, mk, 64);
  __shared__ float red[4];
  int t = threadIdx.x;
  if ((t & 63) == 0) red[t >> 6] = local;
  __syncthreads();
  if (t == 0) atomicAdd(out, -(red[0] + red[1] + red[2] + red[3]) / (float)TWOB);
}

extern "C" void kernel_launch(void* const* d_in, const int* in_sizes, int n_in,
                              void* d_out, int out_size, void* d_ws, size_t ws_size,
                              hipStream_t stream) {
  const float* centers  = (const float*)d_in[0];
  const float* features = (const float*)d_in[1];
  const int*   targets  = (const int*)d_in[2];

  char* ws = (char*)d_ws;
  int*            cnt    = (int*)ws;
  float*          Eacc   = (float*)(ws + 512);
  float*          Sacc   = (float*)(ws + 33280);
  int*            tgtAll = (int*)(ws + 66048);
  float*          rcp0   = (float*)(ws + 99328);
  float*          rcp1   = (float*)(ws + 132608);
  unsigned short* fbB    = (unsigned short*)(ws + 165888);
  unsigned short* fbA    = (unsigned short*)(ws + 2295808);
  float* out = (float*)d_out;

  hipMemsetAsync(ws, 0, 66048, stream);           // cnt + Eacc + Sacc
  hipMemsetAsync(d_out, 0, sizeof(float), stream);
  count_kernel<<<(B_ + 255) / 256, 256, 0, stream>>>(targets, cnt);
  prep_kernel<<<(NJP * 32 + 255) / 256, 256, 0, stream>>>(centers, features, targets, cnt,
                                                          fbB, fbA, tgtAll, rcp0, rcp1);
  dim3 grid(TWOB / 128, 8);   // 64 i-tiles x 8 j-strips = 512 blocks (2/CU)
  bal_mfma<<<grid, 256, 0, stream>>>(fbA, fbB, tgtAll, rcp0, rcp1, Eacc, Sacc);
  bal_final<<<TWOB / 256, 256, 0, stream>>>(tgtAll, cnt, Eacc, Sacc, out);
}

// Round 6
// 141.581 us; speedup vs baseline: 3.0361x; 1.1984x over previous
//
#include <hip/hip_runtime.h>
#include <math.h>

constexpr int B_   = 4096;
constexpr int C_   = 100;
constexpr int D_   = 128;
constexpr int TWOB = 8192;
constexpr int NJ   = 8292;
constexpr int NJP  = 8320;          // padded cols (260 tiles of 32)
constexpr float LOG2E10 = 14.4269504089f;   // 10 * log2(e)

typedef __attribute__((ext_vector_type(8))) short short8;
typedef __attribute__((ext_vector_type(4))) float f32x4;

// ---------------- ws layout (bytes) ----------------
// 0       : int    cnt[128]           512
// 512     : float  Eacc[8192]       32768   -> 33280
// 33280   : float  G[100*128]       51200   -> 84480   (class feature sums)
// 84480   : float4 tbl[8320]       133120   -> 217600  (.x=jt bits, .y=r0, .z=r1)
// 217600  : ushort fbB[8320*128]  2129920   -> 2347520 (unscaled bf16)
// 2347520 : ushort fbA[8192*128]  2097152   -> 4444672 (bf16 of feat*14.4269504)

__device__ __forceinline__ const float* feat_row(const float* __restrict__ centers,
                                                 const float* __restrict__ features,
                                                 int idx) {
  if (idx < B_)   return features + (size_t)idx * (2 * D_);
  if (idx < TWOB) return features + (size_t)(idx - B_) * (2 * D_) + D_;
  return centers + (size_t)(idx - TWOB) * D_;
}

__device__ __forceinline__ unsigned short f2bf(float x) {
  unsigned int u = __float_as_uint(x);
  unsigned int r = (u + 0x7FFFu + ((u >> 16) & 1u)) >> 16;   // RNE
  return (unsigned short)r;
}

__device__ __forceinline__ float bf2f(short s) {
  return __uint_as_float(((unsigned int)(unsigned short)s) << 16);
}

__global__ void count_kernel(const int* __restrict__ targets, int* __restrict__ cnt) {
  int i = blockIdx.x * 256 + threadIdx.x;
  if (i < B_) atomicAdd(&cnt[targets[i]], 1);
}

__global__ __launch_bounds__(256)
void prep_kernel(const float* __restrict__ centers, const float* __restrict__ features,
                 const int* __restrict__ targets, const int* __restrict__ cnt,
                 unsigned short* __restrict__ fbB, unsigned short* __restrict__ fbA,
                 float4* __restrict__ tbl, float* __restrict__ G) {
  int gidx = blockIdx.x * 256 + threadIdx.x;      // NJP*32 items
  if (gidx >= NJP * 32) return;
  int row = gidx >> 5;
  int q   = gidx & 31;                            // float4 index within row
  float4 v = make_float4(0.f, 0.f, 0.f, 0.f);
  int jt = -9;
  if (row < NJ) {
    v  = *(const float4*)(feat_row(centers, features, row) + q * 4);
    jt = (row < B_) ? targets[row] : (row < TWOB ? targets[row - B_] : row - TWOB);
  }
  ushort4 o;
  o.x = f2bf(v.x); o.y = f2bf(v.y); o.z = f2bf(v.z); o.w = f2bf(v.w);
  *(ushort4*)&fbB[(size_t)row * 128 + q * 4] = o;
  if (row < TWOB) {
    ushort4 a;
    a.x = f2bf(v.x * LOG2E10); a.y = f2bf(v.y * LOG2E10);
    a.z = f2bf(v.z * LOG2E10); a.w = f2bf(v.w * LOG2E10);
    *(ushort4*)&fbA[(size_t)row * 128 + q * 4] = a;
  }
  if (row < NJ) {
    // class feature sums over bf16-rounded values (match MFMA arithmetic)
    float* gc = G + jt * 128 + q * 4;
    atomicAdd(gc + 0, bf2f((short)o.x));
    atomicAdd(gc + 1, bf2f((short)o.y));
    atomicAdd(gc + 2, bf2f((short)o.z));
    atomicAdd(gc + 3, bf2f((short)o.w));
  }
  if (q == 0) {
    float r0 = 0.f, r1 = 0.f;
    if (jt >= 0) {
      float b = (float)(2 * cnt[jt] + 1);
      r0 = 1.f / b;
      r1 = 1.f / (b - 1.f);
    }
    tbl[row] = make_float4(__int_as_float(jt), r0, r1, 0.f);
  }
}

// Wave-independent 64x32 MFMA tiles, no LDS, no barriers.
// Grid 512 blocks: id = strip(16) + 16*isuper(32); id%8 = strip%8 -> 2 strips/XCD.
__global__ __launch_bounds__(256, 2)
void bal_mfma(const unsigned short* __restrict__ fbA, const unsigned short* __restrict__ fbB,
              const float4* __restrict__ tbl, float* __restrict__ Eacc) {
  const int t     = threadIdx.x;
  const int lane  = t & 63;
  const int w     = t >> 6;
  const int id    = blockIdx.x;
  const int strip = id & 15;
  const int isup  = id >> 4;
  const int rbase = isup * 256 + w * 64;
  const int lr    = lane & 15;
  const int lh    = lane >> 4;

  const int jg0 = strip * 16 + (strip < 4 ? strip : 4);
  const int jg1 = jg0 + 16 + (strip < 4 ? 1 : 0);     // 260 tiles of 32 cols

  // ---- A fragments (scaled copy), held for the whole strip ----
  short8 af[4][4];                  // [ks][m]
  #pragma unroll
  for (int ks = 0; ks < 4; ++ks)
    #pragma unroll
    for (int m = 0; m < 4; ++m)
      af[ks][m] = *(const short8*)&fbA[(size_t)(rbase + m * 16 + lr) * 128 + (ks * 4 + lh) * 8];

  int ti[4][4];
  #pragma unroll
  for (int m = 0; m < 4; ++m)
    #pragma unroll
    for (int g = 0; g < 4; ++g)
      ti[m][g] = __float_as_int(tbl[rbase + m * 16 + lh * 4 + g].x);

  float ep[4][4];
  #pragma unroll
  for (int m = 0; m < 4; ++m)
    #pragma unroll
    for (int g = 0; g < 4; ++g) ep[m][g] = 0.f;

  short8 b0[2][4], b1[2][4];        // [n][ks]
  float4 t0[2], t1[2];

  auto loadB = [&](int jg, short8 (&b)[2][4], float4 (&tb)[2]) {
    int jb = jg * 32;
    #pragma unroll
    for (int n = 0; n < 2; ++n) {
      tb[n] = tbl[jb + n * 16 + lr];
      #pragma unroll
      for (int ks = 0; ks < 4; ++ks)
        b[n][ks] = *(const short8*)&fbB[(size_t)(jb + n * 16 + lr) * 128 + (ks * 4 + lh) * 8];
    }
  };

  auto compute = [&](short8 (&b)[2][4], float4 (&tb)[2]) {
    f32x4 acc[4][2];
    #pragma unroll
    for (int m = 0; m < 4; ++m)
      #pragma unroll
      for (int n = 0; n < 2; ++n) acc[m][n] = (f32x4){0.f, 0.f, 0.f, 0.f};
    #pragma unroll
    for (int ks = 0; ks < 4; ++ks)
      #pragma unroll
      for (int n = 0; n < 2; ++n)
        #pragma unroll
        for (int m = 0; m < 4; ++m)
          acc[m][n] = __builtin_amdgcn_mfma_f32_16x16x32_bf16(af[ks][m], b[n][ks], acc[m][n], 0, 0, 0);
    #pragma unroll
    for (int n = 0; n < 2; ++n) {
      int   jtn = __float_as_int(tb[n].x);
      float r0  = tb[n].y, r1 = tb[n].z;
      #pragma unroll
      for (int m = 0; m < 4; ++m)
        #pragma unroll
        for (int g = 0; g < 4; ++g) {
          float e = __builtin_amdgcn_exp2f(acc[m][n][g]);   // exp(10*dot)
          ep[m][g] = fmaf(e, (ti[m][g] == jtn) ? r1 : r0, ep[m][g]);
        }
    }
  };

  // ---- ping-pong over the strip ----
  int jg = jg0;
  loadB(jg0, b0, t0);
  while (jg + 2 <= jg1) {
    loadB(jg + 1, b1, t1);
    compute(b0, t0);
    if (jg + 2 < jg1) loadB(jg + 2, b0, t0);
    compute(b1, t1);
    jg += 2;
  }
  if (jg < jg1) compute(b0, t0);

  // ---- reduce over the 16 column-lanes, atomic per row ----
  #pragma unroll
  for (int mk = 1; mk <= 8; mk <<= 1)
    #pragma unroll
    for (int m = 0; m < 4; ++m)
      #pragma unroll
      for (int g = 0; g < 4; ++g)
        ep[m][g] += __shfl_xor(ep[m][g], mk, 64);
  if (lr == 0) {
    #pragma unroll
    for (int m = 0; m < 4; ++m)
      #pragma unroll
      for (int g = 0; g < 4; ++g)
        atomicAdd(&Eacc[rbase + m * 16 + lh * 4 + g], ep[m][g]);
  }
}

// Per-row finish: diag subtraction (exact MFMA-matching self-dot) + analytic
// positive-sum via class sums G, then mean.
__global__ __launch_bounds__(256)
void bal_final(const unsigned short* __restrict__ fbA, const unsigned short* __restrict__ fbB,
               const float4* __restrict__ tbl, const float* __restrict__ G,
               const float* __restrict__ Eacc, float* __restrict__ out) {
  int t    = threadIdx.x;
  int row  = blockIdx.x * 64 + (t >> 2);       // 128 blocks x 64 rows
  int part = t & 3;                             // 32 dims per lane-part
  const unsigned short* pa = fbA + (size_t)row * 128 + part * 32;
  const unsigned short* pb = fbB + (size_t)row * 128 + part * 32;
  float4 tb = tbl[row];
  int   ti  = __float_as_int(tb.x);
  const float* gp = G + ti * 128 + part * 32;

  float sA = 0.f, sB = 0.f, sG = 0.f;
  #pragma unroll
  for (int q = 0; q < 4; ++q) {
    short8 va = *(const short8*)&pa[q * 8];
    short8 vb = *(const short8*)&pb[q * 8];
    #pragma unroll
    for (int d = 0; d < 8; ++d) {
      float fa = bf2f(va[d]);
      float fb = bf2f(vb[d]);
      float gv = gp[q * 8 + d];
      sA = fmaf(fa, fb, sA);    // scaled self-dot, matches MFMA diag acc
      sB = fmaf(fb, fb, sB);    // unscaled self-dot
      sG = fmaf(fb, gv, sG);    // dot with class sum
    }
  }
  sA += __shfl_xor(sA, 1, 64); sA += __shfl_xor(sA, 2, 64);
  sB += __shfl_xor(sB, 1, 64); sB += __shfl_xor(sB, 2, 64);
  sG += __shfl_xor(sG, 1, 64); sG += __shfl_xor(sG, 2, 64);

  float r1 = tb.z;                               // 1/(2*cnt[ti])
  float ep = Eacc[row] - __builtin_amdgcn_exp2f(sA) * r1;
  float ma = 10.f * (sG - sB);                   // sum of mask*logit
  float li = ma * r1 - logf(ep);
  // each row has 4 identical lane-copies -> pre-scale by 1/4; full-wave
  // butterfly then leaves the exact wave total in every lane.
  float local = -li * (1.f / (8192.f * 4.f));

  #pragma unroll
  for (int mk = 1; mk < 64; mk <<= 1) local += __shfl_xor(local, mk, 64);
  if ((t & 63) == 0) atomicAdd(out, local);
}

extern "C" void kernel_launch(void* const* d_in, const int* in_sizes, int n_in,
                              void* d_out, int out_size, void* d_ws, size_t ws_size,
                              hipStream_t stream) {
  const float* centers  = (const float*)d_in[0];
  const float* features = (const float*)d_in[1];
  const int*   targets  = (const int*)d_in[2];

  char* ws = (char*)d_ws;
  int*            cnt  = (int*)ws;
  float*          Eacc = (float*)(ws + 512);
  float*          G    = (float*)(ws + 33280);
  float4*         tbl  = (float4*)(ws + 84480);
  unsigned short* fbB  = (unsigned short*)(ws + 217600);
  unsigned short* fbA  = (unsigned short*)(ws + 2347520);
  float* out = (float*)d_out;

  hipMemsetAsync(ws, 0, 84480, stream);          // cnt + Eacc + G
  hipMemsetAsync(d_out, 0, sizeof(float), stream);
  count_kernel<<<(B_ + 255) / 256, 256, 0, stream>>>(targets, cnt);
  prep_kernel<<<(NJP * 32 + 255) / 256, 256, 0, stream>>>(centers, features, targets, cnt,
                                                          fbB, fbA, tbl, G);
  bal_mfma<<<512, 256, 0, stream>>>(fbA, fbB, tbl, Eacc);
  bal_final<<<TWOB / 64, 256, 0, stream>>>(fbA, fbB, tbl, G, Eacc, out);
}